// Round 7
// baseline (376.720 us; speedup 1.0000x reference)
//
#include <hip/hip_runtime.h>

#define NE 32
#define NT 2048
#define NH 1024
#define NI 512
#define NK 4
#define CAP 512

typedef __attribute__((ext_vector_type(8))) short short8;
typedef __attribute__((ext_vector_type(4))) float floatx4;

#define VMWAIT(n) asm volatile("s_waitcnt vmcnt(" #n ")" ::: "memory")
#define FBAR() do { __builtin_amdgcn_sched_barrier(0);              \
                    __builtin_amdgcn_s_barrier();                   \
                    __builtin_amdgcn_sched_barrier(0); } while (0)

// async global -> LDS, 16B per lane; lds dest is wave-uniform base + lane*16
static __device__ __forceinline__ void gload16(const void* g, void* l) {
    __builtin_amdgcn_global_load_lds(
        (const __attribute__((address_space(1))) unsigned int*)g,
        (__attribute__((address_space(3))) unsigned int*)l, 16, 0, 0);
}

// ---- fp32 -> bf16 (RNE) pair pack -> one dword ----
static __device__ __forceinline__ unsigned pk_bf16(float x, float y) {
#if __has_builtin(__builtin_amdgcn_cvt_pk_bf16_f32)
    typedef __attribute__((ext_vector_type(2))) __bf16 bf16x2;
    union { bf16x2 v; unsigned u; } c;
    c.v = __builtin_amdgcn_cvt_pk_bf16_f32(x, y);
    return c.u;
#else
    union { float f; unsigned u; } a, b;
    a.f = x; b.f = y;
    unsigned ua = (a.u + 0x7fffu + ((a.u >> 16) & 1u)) >> 16;
    unsigned ub = (b.u + 0x7fffu + ((b.u >> 16) & 1u)) >> 16;
    return (ua & 0xffffu) | (ub << 16);
#endif
}

static __device__ __forceinline__ short8 pack8(const float* p) {
    union { unsigned u[4]; short8 s; } c;
    c.u[0] = pk_bf16(p[0], p[1]);
    c.u[1] = pk_bf16(p[2], p[3]);
    c.u[2] = pk_bf16(p[4], p[5]);
    c.u[3] = pk_bf16(p[6], p[7]);
    return c.s;
}

static __device__ __forceinline__ unsigned short bf16_1(float x) {
    return (unsigned short)(pk_bf16(x, 0.f) & 0xffffu);
}

// ---------------- routing ----------------
__global__ void route_kernel(const int* __restrict__ idx,
                             const float* __restrict__ w,
                             int* __restrict__ counts,
                             int* __restrict__ tok,
                             float* __restrict__ wgt) {
    int tid = blockIdx.x * blockDim.x + threadIdx.x;
    if (tid >= NT * NK) return;
    int e = idx[tid];
    int pos = atomicAdd(&counts[e], 1);
    if (pos < CAP) {
        tok[e * CAP + pos] = tid;          // tid = t*NK + k
        wgt[e * CAP + pos] = w[tid];
    }
}

// ---------------- hidden fp32 -> bf16 ----------------
__global__ void cvt_hidden(const float* __restrict__ hidden,
                           unsigned short* __restrict__ hb16) {
    size_t i = (size_t)(blockIdx.x * 256 + threadIdx.x) * 8;
    float tmp[8];
    *(floatx4*)tmp       = *(const floatx4*)(hidden + i);
    *(floatx4*)(tmp + 4) = *(const floatx4*)(hidden + i + 4);
    *(short8*)(hb16 + i) = pack8(tmp);
}

// ---------------- gate/up MFMA GEMM + SiLU ----------------
// tile: 128 entries x 64 j (gate AND up => 128 B-rows), BK=32, 32 K-tiles
// staging 100% via global_load_lds (async, no VGPR round-trip)
// LDS dbuf 48KB -> 3 blocks/CU; counted vmcnt(6): next tile in flight across barrier
// A LDS [128][32]bf16 linear (64B rows = natural bank interleave)
// B LDS [128][32]f32, chunk-XOR-swizzled via pre-swizzled GLOBAL source (LDS linear)
__global__ __launch_bounds__(256, 3) void gateup_mfma(
    const unsigned short* __restrict__ hb16,   // [NT][NH] bf16
    const float* __restrict__ gup,             // [NE][2*NI][NH] fp32
    const int* __restrict__ counts,
    const int* __restrict__ tok,
    unsigned short* __restrict__ hbuf)         // [NT*NK][NI] bf16
{
    int e = blockIdx.z;
    int cnt = counts[e];
    int m0 = blockIdx.y * 128;
    if (m0 >= cnt) return;
    int j0 = blockIdx.x * 64;

    // buf0: A@0 (8K) B@8192 (16K) | buf1: A@24576 B@32768 ; epilogue upb overlay
    __shared__ __align__(16) char smem[49152];
    __shared__ int tks[128];

    int tid = threadIdx.x;
    if (tid < 128) {
        int mi = m0 + tid;
        tks[tid] = tok[e * CAP + (mi < cnt ? mi : m0)];
    }
    __syncthreads();

    int lane = tid & 63, wave = tid >> 6;

    // A staging: wave covers rows [wave*32, wave*32+32), 2 instr x 1KB; 4 lanes/row
    const unsigned short* aptr[2];
#pragma unroll
    for (int i = 0; i < 2; i++) {
        int ar = wave * 32 + i * 16 + (lane >> 2);
        aptr[i] = hb16 + (size_t)(tks[ar] >> 2) * NH + (lane & 3) * 8;
    }
    // B staging: wave covers rows [wave*32, +32), 4 instr x 1KB; 8 lanes/row
    // source chunk pre-swizzled: LDS chunk c holds global chunk c ^ (row&7)
    const float* gup_e = gup + (size_t)e * (2 * NI) * NH;
    const float* bptr[4];
#pragma unroll
    for (int i = 0; i < 4; i++) {
        int br = wave * 32 + i * 8 + (lane >> 3);
        int gc = (lane & 7) ^ (br & 7);
        int grow = (br < 64) ? (j0 + br) : (NI + j0 + (br - 64));
        bptr[i] = gup_e + (size_t)grow * NH + gc * 4;
    }

    char* const A0 = smem;
    char* const B0 = smem + 8192;
    char* const A1 = smem + 24576;
    char* const B1 = smem + 32768;

    int wm = wave >> 1;          // row half
    int wv = wave & 1;           // 0: gate, 1: up
    int lcol = lane & 15;
    int quad = lane >> 4;

    floatx4 acc[4][4];
#pragma unroll
    for (int a = 0; a < 4; a++)
#pragma unroll
        for (int b = 0; b < 4; b++) acc[a][b] = (floatx4){0.f, 0.f, 0.f, 0.f};

    auto stage = [&](char* dA, char* dB, int h) {
#pragma unroll
        for (int i = 0; i < 2; i++)
            gload16(aptr[i] + h, dA + wave * 2048 + i * 1024);
#pragma unroll
        for (int i = 0; i < 4; i++)
            gload16(bptr[i] + h, dB + wave * 4096 + i * 1024);
    };
    auto mfma_step = [&](const char* sA, const char* sB) {
        short8 af[4], bfr[4];
#pragma unroll
        for (int mt = 0; mt < 4; mt++) {
            int r = wm * 64 + mt * 16 + lcol;
            af[mt] = *(const short8*)(sA + r * 64 + quad * 16);
        }
#pragma unroll
        for (int nt = 0; nt < 4; nt++) {
            int r = wv * 64 + nt * 16 + lcol;
            const char* rb = sB + r * 128;
            float4 lo = *(const float4*)(rb + (((quad * 2)     ^ (r & 7)) * 16));
            float4 hi = *(const float4*)(rb + (((quad * 2 + 1) ^ (r & 7)) * 16));
            union { unsigned u[4]; short8 s; } c;
            c.u[0] = pk_bf16(lo.x, lo.y);
            c.u[1] = pk_bf16(lo.z, lo.w);
            c.u[2] = pk_bf16(hi.x, hi.y);
            c.u[3] = pk_bf16(hi.z, hi.w);
            bfr[nt] = c.s;
        }
#pragma unroll
        for (int mt = 0; mt < 4; mt++)
#pragma unroll
            for (int nt = 0; nt < 4; nt++)
                acc[mt][nt] = __builtin_amdgcn_mfma_f32_16x16x32_bf16(
                    af[mt], bfr[nt], acc[mt][nt], 0, 0, 0);
    };

    stage(A0, B0, 0);
    for (int kk = 0; kk < 32; kk += 2) {
        stage(A1, B1, (kk + 1) * 32);
        VMWAIT(6);                 // tile kk complete; tile kk+1 stays in flight
        FBAR();
        mfma_step(A0, B0);
        FBAR();
        if (kk + 2 < 32) { stage(A0, B0, (kk + 2) * 32); VMWAIT(6); }
        else             { VMWAIT(0); }
        FBAR();
        mfma_step(A1, B1);
        FBAR();
    }

    // epilogue: up waves park acc in LDS; gate waves fuse SiLU, store bf16
    float (*upb)[64][68] = (float(*)[64][68])smem;
    if (wv == 1) {
#pragma unroll
        for (int mt = 0; mt < 4; mt++)
#pragma unroll
            for (int nt = 0; nt < 4; nt++)
#pragma unroll
                for (int i = 0; i < 4; i++)
                    upb[wm][mt * 16 + quad * 4 + i][nt * 16 + lcol] = acc[mt][nt][i];
    }
    __syncthreads();
    if (wv == 0) {
#pragma unroll
        for (int mt = 0; mt < 4; mt++) {
#pragma unroll
            for (int i = 0; i < 4; i++) {
                int lm = mt * 16 + quad * 4 + i;
                int m = wm * 64 + lm;
                if (m0 + m < cnt) {
                    unsigned short* hp = hbuf + (size_t)tks[m] * NI + j0;
#pragma unroll
                    for (int nt = 0; nt < 4; nt++) {
                        float g = acc[mt][nt][i];
                        float u = upb[wm][lm][nt * 16 + lcol];
                        float h = g / (1.f + __expf(-g)) * u;
                        hp[nt * 16 + lcol] = bf16_1(h);
                    }
                }
            }
        }
    }
}

// ---------------- down MFMA GEMM + weight-scale ----------------
// tile: 128 entries x 128 H-cols, BK=32 over NI (16 tiles), same async schedule
template<bool ATOMIC>
__global__ __launch_bounds__(256, 3) void down_mfma(
    const unsigned short* __restrict__ hbuf,   // [NT*NK][NI] bf16
    const float* __restrict__ dwn,             // [NE][NH][NI] fp32
    const int* __restrict__ counts,
    const int* __restrict__ tok,
    const float* __restrict__ wgt,
    float* __restrict__ outp)                  // ATOMIC: out[NT][NH] ; else pairbuf[NT*NK][NH]
{
    int e = blockIdx.z;
    int cnt = counts[e];
    int m0 = blockIdx.y * 128;
    if (m0 >= cnt) return;
    int n0 = blockIdx.x * 128;

    __shared__ __align__(16) char smem[49152];
    __shared__ int tks[128];
    __shared__ float wls[128];

    int tid = threadIdx.x;
    if (tid < 128) {
        int mi = m0 + tid;
        int src = e * CAP + (mi < cnt ? mi : m0);
        tks[tid] = tok[src];
        wls[tid] = wgt[src];
    }
    __syncthreads();

    int lane = tid & 63, wave = tid >> 6;

    const unsigned short* aptr[2];
#pragma unroll
    for (int i = 0; i < 2; i++) {
        int ar = wave * 32 + i * 16 + (lane >> 2);
        aptr[i] = hbuf + (size_t)tks[ar] * NI + (lane & 3) * 8;
    }
    const float* dwn_e = dwn + (size_t)e * NH * NI;
    const float* bptr[4];
#pragma unroll
    for (int i = 0; i < 4; i++) {
        int br = wave * 32 + i * 8 + (lane >> 3);
        int gc = (lane & 7) ^ (br & 7);
        bptr[i] = dwn_e + (size_t)(n0 + br) * NI + gc * 4;
    }

    char* const A0 = smem;
    char* const B0 = smem + 8192;
    char* const A1 = smem + 24576;
    char* const B1 = smem + 32768;

    int wm = wave >> 1, wn = wave & 1;
    int lcol = lane & 15;
    int quad = lane >> 4;

    floatx4 acc[4][4];
#pragma unroll
    for (int a = 0; a < 4; a++)
#pragma unroll
        for (int b = 0; b < 4; b++) acc[a][b] = (floatx4){0.f, 0.f, 0.f, 0.f};

    auto stage = [&](char* dA, char* dB, int h) {
#pragma unroll
        for (int i = 0; i < 2; i++)
            gload16(aptr[i] + h, dA + wave * 2048 + i * 1024);
#pragma unroll
        for (int i = 0; i < 4; i++)
            gload16(bptr[i] + h, dB + wave * 4096 + i * 1024);
    };
    auto mfma_step = [&](const char* sA, const char* sB) {
        short8 af[4], bfr[4];
#pragma unroll
        for (int mt = 0; mt < 4; mt++) {
            int r = wm * 64 + mt * 16 + lcol;
            af[mt] = *(const short8*)(sA + r * 64 + quad * 16);
        }
#pragma unroll
        for (int nt = 0; nt < 4; nt++) {
            int r = wn * 64 + nt * 16 + lcol;
            const char* rb = sB + r * 128;
            float4 lo = *(const float4*)(rb + (((quad * 2)     ^ (r & 7)) * 16));
            float4 hi = *(const float4*)(rb + (((quad * 2 + 1) ^ (r & 7)) * 16));
            union { unsigned u[4]; short8 s; } c;
            c.u[0] = pk_bf16(lo.x, lo.y);
            c.u[1] = pk_bf16(lo.z, lo.w);
            c.u[2] = pk_bf16(hi.x, hi.y);
            c.u[3] = pk_bf16(hi.z, hi.w);
            bfr[nt] = c.s;
        }
#pragma unroll
        for (int mt = 0; mt < 4; mt++)
#pragma unroll
            for (int nt = 0; nt < 4; nt++)
                acc[mt][nt] = __builtin_amdgcn_mfma_f32_16x16x32_bf16(
                    af[mt], bfr[nt], acc[mt][nt], 0, 0, 0);
    };

    stage(A0, B0, 0);
    for (int kk = 0; kk < 16; kk += 2) {
        stage(A1, B1, (kk + 1) * 32);
        VMWAIT(6);
        FBAR();
        mfma_step(A0, B0);
        FBAR();
        if (kk + 2 < 16) { stage(A0, B0, (kk + 2) * 32); VMWAIT(6); }
        else             { VMWAIT(0); }
        FBAR();
        mfma_step(A1, B1);
        FBAR();
    }

#pragma unroll
    for (int mt = 0; mt < 4; mt++)
#pragma unroll
        for (int i = 0; i < 4; i++) {
            int m = wm * 64 + mt * 16 + quad * 4 + i;
            if (m0 + m < cnt) {
                float wl = wls[m];
                if (ATOMIC) {
                    float* op = outp + (size_t)(tks[m] >> 2) * NH + n0 + wn * 64;
#pragma unroll
                    for (int nt = 0; nt < 4; nt++)
                        atomicAdd(op + nt * 16 + lcol, acc[mt][nt][i] * wl);
                } else {
                    float* op = outp + (size_t)tks[m] * NH + n0 + wn * 64;
#pragma unroll
                    for (int nt = 0; nt < 4; nt++)
                        op[nt * 16 + lcol] = acc[mt][nt][i] * wl;
                }
            }
        }
}

// ---------------- per-token reduction over the K=4 pair rows ----------------
__global__ void reduce_pairs(const float* __restrict__ pairbuf,
                             float* __restrict__ out) {
    int i = blockIdx.x * 256 + threadIdx.x;      // over NT*NH/4
    int t = i / (NH / 4);
    int c = (i - t * (NH / 4)) * 4;
    const float* p = pairbuf + (size_t)t * NK * NH + c;
    floatx4 a = *(const floatx4*)p;
    a += *(const floatx4*)(p + NH);
    a += *(const floatx4*)(p + 2 * NH);
    a += *(const floatx4*)(p + 3 * NH);
    *(floatx4*)(out + (size_t)t * NH + c) = a;
}

extern "C" void kernel_launch(void* const* d_in, const int* in_sizes, int n_in,
                              void* d_out, int out_size, void* d_ws, size_t ws_size,
                              hipStream_t stream) {
    const float* hidden = (const float*)d_in[0];
    const int*   tk_idx = (const int*)d_in[1];
    const float* tk_w   = (const float*)d_in[2];
    const float* gup    = (const float*)d_in[3];
    const float* dwn    = (const float*)d_in[4];
    float* out = (float*)d_out;

    char* ws = (char*)d_ws;
    int*            counts = (int*)ws;                                            // 256 B
    int*            tok    = (int*)(ws + 256);                                    // 64 KB
    float*          wgt    = (float*)(ws + 256 + NE * CAP * 4);                   // 64 KB
    unsigned short* hb16   = (unsigned short*)(ws + 256 + 2 * NE * CAP * 4);      // 4 MB
    unsigned short* hbuf   = (unsigned short*)(ws + 256 + 2 * NE * CAP * 4
                                               + (size_t)NT * NH * 2);            // 8 MB
    float*          pairbuf = (float*)(ws + 256 + 2 * NE * CAP * 4
                                       + (size_t)NT * NH * 2
                                       + (size_t)NT * NK * NI * 2);               // 32 MB

    size_t need = 256 + 2 * (size_t)NE * CAP * 4 + (size_t)NT * NH * 2
                + (size_t)NT * NK * NI * 2 + (size_t)NT * NK * NH * 4;
    bool pair_ok = ws_size >= need;

    hipMemsetAsync(counts, 0, 256, stream);

    route_kernel<<<(NT * NK + 255) / 256, 256, 0, stream>>>(tk_idx, tk_w, counts, tok, wgt);
    cvt_hidden<<<(NT * NH / 8) / 256, 256, 0, stream>>>(hidden, hb16);

    dim3 gridG(NI / 64, CAP / 128, NE);    // (8, 4, 32)
    gateup_mfma<<<gridG, 256, 0, stream>>>(hb16, gup, counts, tok, hbuf);

    dim3 gridD(NH / 128, CAP / 128, NE);   // (8, 4, 32)
    if (pair_ok) {
        down_mfma<false><<<gridD, 256, 0, stream>>>(hbuf, dwn, counts, tok, wgt, pairbuf);
        reduce_pairs<<<(NT * NH / 4) / 256, 256, 0, stream>>>(pairbuf, out);
    } else {
        hipMemsetAsync(out, 0, (size_t)NT * NH * sizeof(float), stream);
        down_mfma<true><<<gridD, 256, 0, stream>>>(hbuf, dwn, counts, tok, wgt, out);
    }
}

// Round 8
// 343.944 us; speedup vs baseline: 1.0953x; 1.0953x over previous
//
#include <hip/hip_runtime.h>

#define NE 32
#define NT 2048
#define NH 1024
#define NI 512
#define NK 4
#define CAP 512

typedef __attribute__((ext_vector_type(8))) short short8;
typedef __attribute__((ext_vector_type(4))) float floatx4;

#define VMWAIT(n) asm volatile("s_waitcnt vmcnt(" #n ")" ::: "memory")
#define LGKM_BAR() do { __builtin_amdgcn_sched_barrier(0);           \
                        asm volatile("s_waitcnt lgkmcnt(0)" ::: "memory"); \
                        __builtin_amdgcn_s_barrier();                \
                        __builtin_amdgcn_sched_barrier(0); } while (0)

// async global -> LDS, 16B per lane; lds dest = wave-uniform base + lane*16
static __device__ __forceinline__ void gload16(const void* g, void* l) {
    __builtin_amdgcn_global_load_lds(
        (const __attribute__((address_space(1))) unsigned int*)g,
        (__attribute__((address_space(3))) unsigned int*)l, 16, 0, 0);
}

// ---- fp32 -> bf16 (RNE) pair pack -> one dword ----
static __device__ __forceinline__ unsigned pk_bf16(float x, float y) {
#if __has_builtin(__builtin_amdgcn_cvt_pk_bf16_f32)
    typedef __attribute__((ext_vector_type(2))) __bf16 bf16x2;
    union { bf16x2 v; unsigned u; } c;
    c.v = __builtin_amdgcn_cvt_pk_bf16_f32(x, y);
    return c.u;
#else
    union { float f; unsigned u; } a, b;
    a.f = x; b.f = y;
    unsigned ua = (a.u + 0x7fffu + ((a.u >> 16) & 1u)) >> 16;
    unsigned ub = (b.u + 0x7fffu + ((b.u >> 16) & 1u)) >> 16;
    return (ua & 0xffffu) | (ub << 16);
#endif
}

static __device__ __forceinline__ short8 pack8(const float* p) {
    union { unsigned u[4]; short8 s; } c;
    c.u[0] = pk_bf16(p[0], p[1]);
    c.u[1] = pk_bf16(p[2], p[3]);
    c.u[2] = pk_bf16(p[4], p[5]);
    c.u[3] = pk_bf16(p[6], p[7]);
    return c.s;
}

static __device__ __forceinline__ unsigned short bf16_1(float x) {
    return (unsigned short)(pk_bf16(x, 0.f) & 0xffffu);
}

// ---------------- routing ----------------
__global__ void route_kernel(const int* __restrict__ idx,
                             const float* __restrict__ w,
                             int* __restrict__ counts,
                             int* __restrict__ tok,
                             float* __restrict__ wgt) {
    int tid = blockIdx.x * blockDim.x + threadIdx.x;
    if (tid >= NT * NK) return;
    int e = idx[tid];
    int pos = atomicAdd(&counts[e], 1);
    if (pos < CAP) {
        tok[e * CAP + pos] = tid;          // tid = t*NK + k
        wgt[e * CAP + pos] = w[tid];
    }
}

// ---------------- hidden fp32 -> bf16 ----------------
__global__ void cvt_hidden(const float* __restrict__ hidden,
                           unsigned short* __restrict__ hb16) {
    size_t i = (size_t)(blockIdx.x * 256 + threadIdx.x) * 8;
    float tmp[8];
    *(floatx4*)tmp       = *(const floatx4*)(hidden + i);
    *(floatx4*)(tmp + 4) = *(const floatx4*)(hidden + i + 4);
    *(short8*)(hb16 + i) = pack8(tmp);
}

// =====================================================================
// gate/up: tile 256 tokens x 64 j (128 B-rows incl. up), BK=64, 16 K-tiles
// 512 threads = 8 waves (4M x 2N); wave-tile 64 tok x 64 B-rows; acc 4x4
// A: global_load_lds (dist-2, 3 LDS bufs); B: reg-staged fp32->bf16 (dist-2)
// ONE vmcnt(8) + ONE barrier per K-tile. XOR-chunk swizzle (c ^= r&7) on
// both operands: A swizzle applied on the GLOBAL source (linear LDS dest),
// B swizzle applied at ds_write. All frag reads 2-way conflict (free).
// LDS: A 3x32KB @0/32K/64K, B 2x16KB @96K/112K = 128 KB -> 1 block/CU
// =====================================================================
__global__ __launch_bounds__(512, 2) void gateup_mfma(
    const unsigned short* __restrict__ hb16,   // [NT][NH] bf16
    const float* __restrict__ gup,             // [NE][2*NI][NH] fp32
    const int* __restrict__ counts,
    const int* __restrict__ tok,
    unsigned short* __restrict__ hbuf)         // [NT*NK][NI] bf16
{
    const int NTL = NH / 64;                   // 16 K-tiles
    int e = blockIdx.z;
    int cnt = counts[e];
    int m0 = blockIdx.y * 256;
    if (m0 >= cnt) return;
    int j0 = blockIdx.x * 64;

    __shared__ __align__(16) char smem[131072];
    __shared__ int tks[256];

    int tid = threadIdx.x;
    if (tid < 256) {
        int mi = m0 + tid;
        tks[tid] = tok[e * CAP + (mi < cnt ? mi : m0)];
    }
    __syncthreads();

    int lane = tid & 63, wave = tid >> 6;      // wave 0..7
    int wm = wave >> 1, wn = wave & 1;         // wn: 0=gate rows, 1=up rows
    int lcol = lane & 15, quad = lane >> 4;

    // ---- A staging: wave covers rows wave*32..+31; 4 instr x (8 rows x 128B)
    // lane: row = i*8 + (lane>>3), phys chunk = lane&7 holds global chunk ^(r&7)
    const unsigned short* aptr[4];
#pragma unroll
    for (int i = 0; i < 4; i++) {
        int r = wave * 32 + i * 8 + (lane >> 3);
        int gc = (lane & 7) ^ (r & 7);
        aptr[i] = hb16 + (size_t)(tks[r] >> 2) * NH + gc * 8;
    }
    // ---- B staging: wave covers rows wave*16..+15; 4 lanes/row, 4 instr over k
    const float* gup_e = gup + (size_t)e * (2 * NI) * NH;
    int brow = wave * 16 + (lane >> 2);
    int bgrow = (brow < 64) ? (j0 + brow) : (NI + j0 + (brow - 64));
    const float* bsrc = gup_e + (size_t)bgrow * NH + (lane & 3) * 4;
    int wboff[4];
#pragma unroll
    for (int i = 0; i < 4; i++) {
        int c16 = ((lane & 3) >> 1) + i * 2;               // logical 16B chunk
        wboff[i] = brow * 128 + ((c16 ^ (brow & 7)) * 16) + (lane & 1) * 8;
    }

    floatx4 acc[4][4];
#pragma unroll
    for (int a = 0; a < 4; a++)
#pragma unroll
        for (int b = 0; b < 4; b++) acc[a][b] = (floatx4){0.f, 0.f, 0.f, 0.f};

    float4 rbE[4], rbO[4];

    auto stageA = [&](int t) {                 // A(t) -> Abuf[t%3]
        char* d = smem + (size_t)(t % 3) * 32768 + wave * 4096;
#pragma unroll
        for (int i = 0; i < 4; i++)
            gload16(aptr[i] + t * 64, d + i * 1024);
    };
    auto loadB = [&](int t, float4* rb) {
#pragma unroll
        for (int i = 0; i < 4; i++)
            rb[i] = *(const float4*)(bsrc + t * 64 + i * 16);
    };
    auto writeB = [&](int t, const float4* rb) {   // -> Bbuf[t&1]
        char* d = smem + 98304 + (size_t)(t & 1) * 16384;
#pragma unroll
        for (int i = 0; i < 4; i++) {
            uint2 u;
            u.x = pk_bf16(rb[i].x, rb[i].y);
            u.y = pk_bf16(rb[i].z, rb[i].w);
            *(uint2*)(d + wboff[i]) = u;
        }
    };
    auto mfma_t = [&](int t) {
        const char* sA = smem + (size_t)(t % 3) * 32768;
        const char* sB = smem + 98304 + (size_t)(t & 1) * 16384;
#pragma unroll
        for (int ks = 0; ks < 2; ks++) {
            short8 af[4], bfr[4];
#pragma unroll
            for (int mt = 0; mt < 4; mt++) {
                int r = wm * 64 + mt * 16 + lcol;
                af[mt] = *(const short8*)(sA + r * 128 + ((((ks << 2) + quad) ^ (r & 7)) * 16));
            }
#pragma unroll
            for (int nt = 0; nt < 4; nt++) {
                int r = wn * 64 + nt * 16 + lcol;
                bfr[nt] = *(const short8*)(sB + r * 128 + ((((ks << 2) + quad) ^ (r & 7)) * 16));
            }
#pragma unroll
            for (int mt = 0; mt < 4; mt++)
#pragma unroll
                for (int nt = 0; nt < 4; nt++)
                    acc[mt][nt] = __builtin_amdgcn_mfma_f32_16x16x32_bf16(
                        af[mt], bfr[nt], acc[mt][nt], 0, 0, 0);
        }
    };
    // one K-tile phase: issue A(t+2)/B(t+2), write B(t+1), compute t, wait, barrier
    auto phase = [&](int t, float4* rbL, float4* rbW) {
        if (t + 2 < NTL) { stageA(t + 2); loadB(t + 2, rbL); }
        if (t + 1 < NTL) writeB(t + 1, rbW);
        mfma_t(t);
        if (t + 2 < NTL) { VMWAIT(8); } else { VMWAIT(0); }
        LGKM_BAR();
    };

    // ---- prologue: tiles 0,1 in flight ----
    stageA(0); loadB(0, rbE);
    stageA(1); loadB(1, rbO);
    writeB(0, rbE);            // compiler-inserted vmcnt covers rbE; A(0) older
    VMWAIT(8);                 // A(0) definitely complete (A(1),B(1) in flight)
    LGKM_BAR();

    for (int tt = 0; tt < NTL; tt += 2) {
        phase(tt,     rbE, rbO);   // loads B(t+2) even -> rbE; writes B(t+1) from rbO
        phase(tt + 1, rbO, rbE);
    }

    // ---- epilogue: up waves park in LDS; gate waves fuse SiLU, store bf16 ----
    float (*upb)[64][68] = (float(*)[64][68])smem;     // 4*64*68*4 = 69632 B
    if (wn == 1) {
#pragma unroll
        for (int mt = 0; mt < 4; mt++)
#pragma unroll
            for (int nt = 0; nt < 4; nt++)
#pragma unroll
                for (int i = 0; i < 4; i++)
                    upb[wm][mt * 16 + quad * 4 + i][nt * 16 + lcol] = acc[mt][nt][i];
    }
    __syncthreads();
    if (wn == 0) {
#pragma unroll
        for (int mt = 0; mt < 4; mt++) {
#pragma unroll
            for (int i = 0; i < 4; i++) {
                int lm = mt * 16 + quad * 4 + i;
                int m = wm * 64 + lm;
                if (m0 + m < cnt) {
                    unsigned short* hp = hbuf + (size_t)tks[m] * NI + j0;
#pragma unroll
                    for (int nt = 0; nt < 4; nt++) {
                        float g = acc[mt][nt][i];
                        float u = upb[wm][lm][nt * 16 + lcol];
                        float h = g / (1.f + __expf(-g)) * u;
                        hp[nt * 16 + lcol] = bf16_1(h);
                    }
                }
            }
        }
    }
}

// =====================================================================
// down: tile 256 pairs x 128 H-cols, BK=64 over NI (8 K-tiles), same schedule
// =====================================================================
template<bool ATOMIC>
__global__ __launch_bounds__(512, 2) void down_mfma(
    const unsigned short* __restrict__ hbuf,   // [NT*NK][NI] bf16
    const float* __restrict__ dwn,             // [NE][NH][NI] fp32
    const int* __restrict__ counts,
    const int* __restrict__ tok,
    const float* __restrict__ wgt,
    float* __restrict__ outp)                  // ATOMIC: out[NT][NH] ; else pairbuf
{
    const int NTL = NI / 64;                   // 8 K-tiles
    int e = blockIdx.z;
    int cnt = counts[e];
    int m0 = blockIdx.y * 256;
    if (m0 >= cnt) return;
    int n0 = blockIdx.x * 128;

    __shared__ __align__(16) char smem[131072];
    __shared__ int tks[256];
    __shared__ float wls[256];

    int tid = threadIdx.x;
    if (tid < 256) {
        int mi = m0 + tid;
        int src = e * CAP + (mi < cnt ? mi : m0);
        tks[tid] = tok[src];
        wls[tid] = wgt[src];
    }
    __syncthreads();

    int lane = tid & 63, wave = tid >> 6;
    int wm = wave >> 1, wn = wave & 1;
    int lcol = lane & 15, quad = lane >> 4;

    const unsigned short* aptr[4];
#pragma unroll
    for (int i = 0; i < 4; i++) {
        int r = wave * 32 + i * 8 + (lane >> 3);
        int gc = (lane & 7) ^ (r & 7);
        aptr[i] = hbuf + (size_t)tks[r] * NI + gc * 8;
    }
    const float* dwn_e = dwn + (size_t)e * NH * NI;
    int brow = wave * 16 + (lane >> 2);
    const float* bsrc = dwn_e + (size_t)(n0 + brow) * NI + (lane & 3) * 4;
    int wboff[4];
#pragma unroll
    for (int i = 0; i < 4; i++) {
        int c16 = ((lane & 3) >> 1) + i * 2;
        wboff[i] = brow * 128 + ((c16 ^ (brow & 7)) * 16) + (lane & 1) * 8;
    }

    floatx4 acc[4][4];
#pragma unroll
    for (int a = 0; a < 4; a++)
#pragma unroll
        for (int b = 0; b < 4; b++) acc[a][b] = (floatx4){0.f, 0.f, 0.f, 0.f};

    float4 rbE[4], rbO[4];

    auto stageA = [&](int t) {
        char* d = smem + (size_t)(t % 3) * 32768 + wave * 4096;
#pragma unroll
        for (int i = 0; i < 4; i++)
            gload16(aptr[i] + t * 64, d + i * 1024);
    };
    auto loadB = [&](int t, float4* rb) {
#pragma unroll
        for (int i = 0; i < 4; i++)
            rb[i] = *(const float4*)(bsrc + t * 64 + i * 16);
    };
    auto writeB = [&](int t, const float4* rb) {
        char* d = smem + 98304 + (size_t)(t & 1) * 16384;
#pragma unroll
        for (int i = 0; i < 4; i++) {
            uint2 u;
            u.x = pk_bf16(rb[i].x, rb[i].y);
            u.y = pk_bf16(rb[i].z, rb[i].w);
            *(uint2*)(d + wboff[i]) = u;
        }
    };
    auto mfma_t = [&](int t) {
        const char* sA = smem + (size_t)(t % 3) * 32768;
        const char* sB = smem + 98304 + (size_t)(t & 1) * 16384;
#pragma unroll
        for (int ks = 0; ks < 2; ks++) {
            short8 af[4], bfr[4];
#pragma unroll
            for (int mt = 0; mt < 4; mt++) {
                int r = wm * 64 + mt * 16 + lcol;
                af[mt] = *(const short8*)(sA + r * 128 + ((((ks << 2) + quad) ^ (r & 7)) * 16));
            }
#pragma unroll
            for (int nt = 0; nt < 4; nt++) {
                int r = wn * 64 + nt * 16 + lcol;
                bfr[nt] = *(const short8*)(sB + r * 128 + ((((ks << 2) + quad) ^ (r & 7)) * 16));
            }
#pragma unroll
            for (int mt = 0; mt < 4; mt++)
#pragma unroll
                for (int nt = 0; nt < 4; nt++)
                    acc[mt][nt] = __builtin_amdgcn_mfma_f32_16x16x32_bf16(
                        af[mt], bfr[nt], acc[mt][nt], 0, 0, 0);
        }
    };
    auto phase = [&](int t, float4* rbL, float4* rbW) {
        if (t + 2 < NTL) { stageA(t + 2); loadB(t + 2, rbL); }
        if (t + 1 < NTL) writeB(t + 1, rbW);
        mfma_t(t);
        if (t + 2 < NTL) { VMWAIT(8); } else { VMWAIT(0); }
        LGKM_BAR();
    };

    stageA(0); loadB(0, rbE);
    stageA(1); loadB(1, rbO);
    writeB(0, rbE);
    VMWAIT(8);
    LGKM_BAR();

    for (int tt = 0; tt < NTL; tt += 2) {
        phase(tt,     rbE, rbO);
        phase(tt + 1, rbO, rbE);
    }

#pragma unroll
    for (int mt = 0; mt < 4; mt++)
#pragma unroll
        for (int i = 0; i < 4; i++) {
            int m = wm * 64 + mt * 16 + quad * 4 + i;
            if (m0 + m < cnt) {
                float wl = wls[m];
                if (ATOMIC) {
                    float* op = outp + (size_t)(tks[m] >> 2) * NH + n0 + wn * 64;
#pragma unroll
                    for (int nt = 0; nt < 4; nt++)
                        atomicAdd(op + nt * 16 + lcol, acc[mt][nt][i] * wl);
                } else {
                    float* op = outp + (size_t)tks[m] * NH + n0 + wn * 64;
#pragma unroll
                    for (int nt = 0; nt < 4; nt++)
                        op[nt * 16 + lcol] = acc[mt][nt][i] * wl;
                }
            }
        }
}

// ---------------- per-token reduction over the K=4 pair rows ----------------
__global__ void reduce_pairs(const float* __restrict__ pairbuf,
                             float* __restrict__ out) {
    int i = blockIdx.x * 256 + threadIdx.x;      // over NT*NH/4
    int t = i / (NH / 4);
    int c = (i - t * (NH / 4)) * 4;
    const float* p = pairbuf + (size_t)t * NK * NH + c;
    floatx4 a = *(const floatx4*)p;
    a += *(const floatx4*)(p + NH);
    a += *(const floatx4*)(p + 2 * NH);
    a += *(const floatx4*)(p + 3 * NH);
    *(floatx4*)(out + (size_t)t * NH + c) = a;
}

extern "C" void kernel_launch(void* const* d_in, const int* in_sizes, int n_in,
                              void* d_out, int out_size, void* d_ws, size_t ws_size,
                              hipStream_t stream) {
    const float* hidden = (const float*)d_in[0];
    const int*   tk_idx = (const int*)d_in[1];
    const float* tk_w   = (const float*)d_in[2];
    const float* gup    = (const float*)d_in[3];
    const float* dwn    = (const float*)d_in[4];
    float* out = (float*)d_out;

    char* ws = (char*)d_ws;
    int*            counts = (int*)ws;                                            // 256 B
    int*            tok    = (int*)(ws + 256);                                    // 64 KB
    float*          wgt    = (float*)(ws + 256 + NE * CAP * 4);                   // 64 KB
    unsigned short* hb16   = (unsigned short*)(ws + 256 + 2 * NE * CAP * 4);      // 4 MB
    unsigned short* hbuf   = (unsigned short*)(ws + 256 + 2 * NE * CAP * 4
                                               + (size_t)NT * NH * 2);            // 8 MB
    float*          pairbuf = (float*)(ws + 256 + 2 * NE * CAP * 4
                                       + (size_t)NT * NH * 2
                                       + (size_t)NT * NK * NI * 2);               // 32 MB

    size_t need = 256 + 2 * (size_t)NE * CAP * 4 + (size_t)NT * NH * 2
                + (size_t)NT * NK * NI * 2 + (size_t)NT * NK * NH * 4;
    bool pair_ok = ws_size >= need;

    hipMemsetAsync(counts, 0, 256, stream);

    route_kernel<<<(NT * NK + 255) / 256, 256, 0, stream>>>(tk_idx, tk_w, counts, tok, wgt);
    cvt_hidden<<<(NT * NH / 8) / 256, 256, 0, stream>>>(hidden, hb16);

    dim3 gridG(NI / 64, CAP / 256, NE);    // (8, 2, 32), 512 threads
    gateup_mfma<<<gridG, 512, 0, stream>>>(hb16, gup, counts, tok, hbuf);

    dim3 gridD(NH / 128, CAP / 256, NE);   // (8, 2, 32), 512 threads
    if (pair_ok) {
        down_mfma<false><<<gridD, 512, 0, stream>>>(hbuf, dwn, counts, tok, wgt, pairbuf);
        reduce_pairs<<<(NT * NH / 4) / 256, 256, 0, stream>>>(pairbuf, out);
    } else {
        hipMemsetAsync(out, 0, (size_t)NT * NH * sizeof(float), stream);
        down_mfma<true><<<gridD, 512, 0, stream>>>(hbuf, dwn, counts, tok, wgt, out);
    }
}